// Round 9
// baseline (444.533 us; speedup 1.0000x reference)
//
#include <hip/hip_runtime.h>
#include <stdint.h>

#define T_TOK 8192
#define NEXP  8
#define DIMSZ 1024
#define HIDSZ 2048

typedef __attribute__((ext_vector_type(4))) float f32x4;
typedef __attribute__((ext_vector_type(8))) short s16x8;

// ---------- helpers ----------

__device__ __forceinline__ uint16_t f2bf(float f) {
  uint32_t u = __builtin_bit_cast(uint32_t, f);
  u += 0x7fffu + ((u >> 16) & 1u);   // RNE
  return (uint16_t)(u >> 16);
}

__device__ __forceinline__ uint32_t pkbf(float a, float b) {
  return (uint32_t)f2bf(a) | ((uint32_t)f2bf(b) << 16);
}

// convert one 16-float unit (64B read, 32B write)
__device__ __forceinline__ void cvt_unit(const float* __restrict__ src,
                                         uint16_t* __restrict__ dst, size_t j) {
  const float4* p = (const float4*)src + 4 * j;
  float4 a = p[0], b = p[1], c = p[2], d = p[3];
  uint4 o0, o1;
  o0.x = pkbf(a.x, a.y); o0.y = pkbf(a.z, a.w);
  o0.z = pkbf(b.x, b.y); o0.w = pkbf(b.z, b.w);
  o1.x = pkbf(c.x, c.y); o1.y = pkbf(c.z, c.w);
  o1.z = pkbf(d.x, d.y); o1.w = pkbf(d.z, d.w);
  uint4* q = (uint4*)dst + 2 * j;
  q[0] = o0;
  q[1] = o1;
}

// async global->LDS, 16B per lane; LDS dst = wave-uniform base + lane*16.
__device__ __forceinline__ void gload_lds16(const uint16_t* g, const uint16_t* lds_base) {
  __builtin_amdgcn_global_load_lds(
      (const __attribute__((address_space(1))) uint32_t*)(uintptr_t)g,
      (__attribute__((address_space(3))) uint32_t*)(uint32_t)(uintptr_t)lds_base,
      16, 0, 0);
}

// opaque LDS 16B read (compiler can't alias-analyze -> no forced vmcnt drain).
// Caller must s_waitcnt lgkmcnt(0) + sched_barrier(0) before use (rule #18).
__device__ __forceinline__ s16x8 ds_read128(const uint16_t* addr) {
  s16x8 r;
  asm volatile("ds_read_b128 %0, %1"
               : "=v"(r)
               : "v"((uint32_t)(uintptr_t)addr));
  return r;
}

// ---------- convert x + w1 (+ offsets in block 0; 256-granular tile table) ----------

__global__ void cvt_xw1(const float* __restrict__ x, const float* __restrict__ w1,
                        uint16_t* __restrict__ xb, uint16_t* __restrict__ w1b,
                        const int* __restrict__ counts, int* __restrict__ offs,
                        int* __restrict__ toffs) {
  if (blockIdx.x == 0 && threadIdx.x == 0) {
    int s = 0, ts = 0;
    for (int e = 0; e < NEXP; ++e) {
      offs[e] = s; toffs[e] = ts;
      s += counts[e]; ts += (counts[e] + 255) >> 8;   // BM=256 tiles
    }
    offs[NEXP] = s; toffs[NEXP] = ts;
  }
  const int NX = (T_TOK * DIMSZ) / 16;           // 524288
  const int NW = (NEXP * HIDSZ * DIMSZ) / 16;    // 1048576
  const int total = NX + NW;
  const int stride = gridDim.x * blockDim.x;
  for (int i = blockIdx.x * blockDim.x + threadIdx.x; i < total; i += stride) {
    if (i < NX) cvt_unit(x, xb, i);
    else        cvt_unit(w1, w1b, i - NX);
  }
}

// ---------- grouped NT GEMM, BM=256, depth-2 counted-vmcnt pipeline ----------
// C[m,n] = sum_k A[m,k] * B_e[n,k].  512 threads = 8 waves (4M x 2N), BK=64.
// Per-wave output 64 x BN/2.  LDS: As[2] 64KB + Bs[2] (BN=256: 64KB / 128: 32KB).
// Depth-2 schedule (per-wave vmcnt ledger, L = gloads/tile = 4 + BN/64):
//   prologue: STAGE(t0->buf0) STAGE(t1->buf1); vmcnt(L) [t0 done]; barrier
//   step t:   COMPUTE(buf p);  barrier (all reads retired);
//             STAGE(t+2 -> buf p);  vmcnt(L) [t+1 done, t+2 in flight]; barrier
// Counted vmcnt keeps L loads in flight ACROSS the barrier (T4) and every tile
// gets ~2 steps of latency budget.  Raw s_barrier carries no implicit drain.
// Intensity: BM*BN/(BM+BN) = 128 (BN=256) / 85 (BN=128) FLOP/staged-byte vs 64
// at the old 128^2 tile -> same staging B/cyc gives 1.3-2x the FLOP rate.
// T1 bijective XCD remap.  Piggyback: LAST ncvt blocks convert w2 (backfill
// freed CUs during GEMM1's tail; GEMM2 consumes w2b after this kernel).
// Chunk swizzle (proven all session): global chunk q of row r at LDS position
// q ^ ((r>>1)&7); fragment read offset f0 = ((lane>>4)^((fr>>1)&7))*8, ^kk*32.
template <bool OUT_BF16, int BN>
__global__ __launch_bounds__(512, 2)
void gemm_big(const uint16_t* __restrict__ A, const uint16_t* __restrict__ B,
              void* __restrict__ C, const int* __restrict__ offs,
              const int* __restrict__ toffs, int N, int K,
              const float* __restrict__ cvt_src, uint16_t* __restrict__ cvt_dst,
              int ncvt, int cvt_units) {
  constexpr int NBC = BN / 64;        // B stage calls per wave (4 or 2)
  constexpr int L   = 4 + NBC;        // gloads per wave per K-tile (8 or 6)
  constexpr int NR  = (BN / 2) / 16;  // B frags per wave (8 or 4)
  __shared__ __align__(16) uint16_t As0[256 * 64];
  __shared__ __align__(16) uint16_t As1[256 * 64];
  __shared__ __align__(16) uint16_t Bs0[BN * 64];
  __shared__ __align__(16) uint16_t Bs1[BN * 64];

  const int nb = gridDim.x - ncvt;                 // gemm blocks

  // ---- piggyback conversion blocks (tail of grid) ----
  if ((int)blockIdx.x >= nb) {
    const int cb = blockIdx.x - nb;
    const int cstride = ncvt * 512;
    for (int u = cb * 512 + threadIdx.x; u < cvt_units; u += cstride)
      cvt_unit(cvt_src, cvt_dst, u);
    return;
  }

  // ---- T1: bijective XCD-chunked remap ----
  const int orig = blockIdx.x;
  const int qc = nb >> 3, rc = nb & 7, xcd = orig & 7;
  const int bid = (xcd < rc ? xcd * (qc + 1) : rc * (qc + 1) + (xcd - rc) * qc) + (orig >> 3);

  const int mtg = bid >> 3;                        // lognt = 3 for both GEMMs
  const int nt  = bid & 7;
  if (mtg >= toffs[NEXP]) return;
  int e = 0;
#pragma unroll
  for (int i = 1; i < NEXP; ++i) e += (toffs[i] <= mtg) ? 1 : 0;
  const int mt      = mtg - toffs[e];
  const int m_start = offs[e];
  const int m_count = offs[e + 1] - m_start;
  const int m0      = mt * 256;
  int valid_m = m_count - m0;
  if (valid_m > 256) valid_m = 256;
  const int n0 = nt * BN;

  const int tid  = threadIdx.x;
  const int w    = tid >> 6;        // 0..7
  const int lane = tid & 63;
  const int wm = w >> 1, wn = w & 1;

  const uint16_t* gA = A + (size_t)m_start * K;
  const uint16_t* gB = B + (size_t)e * N * K;

  // Staging maps. A: wave w rows w*32+c*8+(lane>>3), c=0..3 (256 rows).
  // B: wave w rows w*8*NBC+c*8+(lane>>3), c=0..NBC-1 (BN rows).
  // Global chunk q8 = ((lane&7) ^ ((r>>1)&7))*8 pre-swizzles the source so the
  // linear LDS write ends up chunk-swizzled.
  const uint16_t* ap[4];
  const uint16_t* bp[NBC];
#pragma unroll
  for (int c = 0; c < 4; ++c) {
    const int r  = w * 32 + c * 8 + (lane >> 3);
    const int q8 = ((lane & 7) ^ ((r >> 1) & 7)) * 8;
    const int ra = (r < valid_m) ? r : (valid_m - 1);
    ap[c] = gA + (size_t)(m0 + ra) * K + q8;
  }
#pragma unroll
  for (int c = 0; c < NBC; ++c) {
    const int r  = w * 8 * NBC + c * 8 + (lane >> 3);
    const int q8 = ((lane & 7) ^ ((r >> 1) & 7)) * 8;
    bp[c] = gB + (size_t)(n0 + r) * K + q8;
  }

  const int fr = lane & 15;
  const int f0 = ((lane >> 4) ^ ((fr >> 1) & 7)) * 8;

  f32x4 acc[4][NR];
#pragma unroll
  for (int mi = 0; mi < 4; ++mi)
#pragma unroll
    for (int ni = 0; ni < NR; ++ni) acc[mi][ni] = (f32x4){0.f, 0.f, 0.f, 0.f};

  const int NT = K >> 6;   // 16 or 32 (even)

#define STAGE(AD, BD)                                                          \
  {                                                                            \
    _Pragma("unroll")                                                          \
    for (int c = 0; c < 4; ++c) {                                              \
      gload_lds16(ap[c], &AD[(w * 32 + c * 8) * 64]);                          \
      ap[c] += 64;                                                             \
    }                                                                          \
    _Pragma("unroll")                                                          \
    for (int c = 0; c < NBC; ++c) {                                            \
      gload_lds16(bp[c], &BD[(w * 8 * NBC + c * 8) * 64]);                     \
      bp[c] += 64;                                                             \
    }                                                                          \
  }

#define WAITVL()                                                               \
  {                                                                            \
    if constexpr (L == 8) { asm volatile("s_waitcnt vmcnt(8)" ::: "memory"); } \
    else                  { asm volatile("s_waitcnt vmcnt(6)" ::: "memory"); } \
  }

#define COMPUTE(AR, BR)                                                        \
  _Pragma("unroll")                                                            \
  for (int kk = 0; kk < 2; ++kk) {                                             \
    const int fk = f0 ^ (kk << 5);                                             \
    s16x8 af[4], bf[NR];                                                       \
    _Pragma("unroll")                                                          \
    for (int mi = 0; mi < 4; ++mi)                                             \
      af[mi] = ds_read128(&AR[(wm * 64 + mi * 16 + fr) * 64 + fk]);            \
    _Pragma("unroll")                                                          \
    for (int ni = 0; ni < NR; ++ni)                                            \
      bf[ni] = ds_read128(&BR[(wn * (BN / 2) + ni * 16 + fr) * 64 + fk]);      \
    asm volatile("s_waitcnt lgkmcnt(0)" ::: "memory");                         \
    __builtin_amdgcn_sched_barrier(0);                                         \
    _Pragma("unroll")                                                          \
    for (int mi = 0; mi < 4; ++mi)                                             \
      _Pragma("unroll")                                                        \
      for (int ni = 0; ni < NR; ++ni)                                          \
        acc[mi][ni] = __builtin_amdgcn_mfma_f32_16x16x32_bf16(                 \
            af[mi], bf[ni], acc[mi][ni], 0, 0, 0);                             \
  }

#define GSTEP(AR, BR, T)                                                       \
  {                                                                            \
    COMPUTE(AR, BR)                                                            \
    if ((T) + 1 < NT) {                                                        \
      __builtin_amdgcn_s_barrier();        /* all reads of AR/BR retired */    \
      __builtin_amdgcn_sched_barrier(0);                                       \
      if ((T) + 2 < NT) {                                                      \
        STAGE(AR, BR)                      /* tile T+2 into freed buffer */    \
        WAITVL()                           /* tile T+1 done; T+2 in flight */  \
      } else {                                                                 \
        asm volatile("s_waitcnt vmcnt(0)" ::: "memory");                       \
      }                                                                        \
      __builtin_amdgcn_s_barrier();                                            \
      __builtin_amdgcn_sched_barrier(0);                                       \
    }                                                                          \
  }

  // ---- prologue: tiles 0,1 -> buf0,buf1; wait tile0; barrier ----
  STAGE(As0, Bs0)
  STAGE(As1, Bs1)
  WAITVL()
  __builtin_amdgcn_s_barrier();
  __builtin_amdgcn_sched_barrier(0);

  for (int t = 0; t < NT; t += 2) {
    GSTEP(As0, Bs0, t);
    GSTEP(As1, Bs1, t + 1);
  }
#undef GSTEP
#undef COMPUTE
#undef WAITVL
#undef STAGE

  // Epilogue. C/D 16x16 layout: col = lane&15, row = (lane>>4)*4 + reg.
  const int cq = (lane >> 4) * 4;
  const int cc = lane & 15;
#pragma unroll
  for (int mi = 0; mi < 4; ++mi) {
#pragma unroll
    for (int r = 0; r < 4; ++r) {
      const int rt = wm * 64 + mi * 16 + cq + r;
      if (rt < valid_m) {
        const size_t rowoff = (size_t)(m_start + m0 + rt) * N;
#pragma unroll
        for (int ni = 0; ni < NR; ++ni) {
          const int col = n0 + wn * (BN / 2) + ni * 16 + cc;
          const float v = acc[mi][ni][r];
          if (OUT_BF16) {
            ((uint16_t*)C)[rowoff + col] = f2bf(v);
          } else {
            const uint32_t b = (uint32_t)f2bf(v) << 16;
            ((float*)C)[rowoff + col] = __builtin_bit_cast(float, b);
          }
        }
      }
    }
  }
}

// ---------- launch ----------

extern "C" void kernel_launch(void* const* d_in, const int* in_sizes, int n_in,
                              void* d_out, int out_size, void* d_ws, size_t ws_size,
                              hipStream_t stream) {
  const float* x  = (const float*)d_in[0];   // [T, DIM]
  const float* w1 = (const float*)d_in[1];   // [E, HID, DIM]
  const float* w2 = (const float*)d_in[2];   // [E, DIM, HID]
  const int* cnt  = (const int*)d_in[3];     // [E]
  float* out = (float*)d_out;                // [T, DIM] f32

  char* ws = (char*)d_ws;
  uint16_t* xb  = (uint16_t*)(ws);                      // 16 MB  [T, DIM] bf16
  uint16_t* w1b = (uint16_t*)(ws + 16777216);           // 32 MB  [E, HID, DIM] bf16
  uint16_t* w2b = (uint16_t*)(ws + 50331648);           // 32 MB  [E, DIM, HID] bf16
  uint16_t* h   = (uint16_t*)(ws + 83886080);           // 32 MB  [T, HID] bf16
  int* offs     = (int*)(ws + 117440512);               // 9 ints
  int* toffs    = offs + 9;                             // 9 ints

  cvt_xw1<<<2048, 256, 0, stream>>>(x, w1, xb, w1b, cnt, offs, toffs);

  const int MAX_MT = T_TOK / 256 + NEXP - 1;            // 39: worst-case m-tiles
  const int NB     = MAX_MT * 8;                        // 312 (lognt=3 both GEMMs)
  const int NCVT   = 256;                               // piggyback w2-cvt blocks
  const int W2U    = (NEXP * DIMSZ * HIDSZ) / 16;       // 1048576 16-float units

  // GEMM1: h = xb @ w1b^T  (BNt=256: N=2048 -> 8 n-tiles; K=DIM)
  // + piggybacked w2 conversion in the LAST NCVT blocks.
  gemm_big<true, 256><<<NB + NCVT, 512, 0, stream>>>(
      xb, w1b, (void*)h, offs, toffs, HIDSZ, DIMSZ, w2, w2b, NCVT, W2U);

  // GEMM2: out = h @ w2b^T  (BNt=128: N=1024 -> 8 n-tiles; K=HID)
  gemm_big<false, 128><<<NB, 512, 0, stream>>>(
      h, w2b, (void*)out, offs, toffs, DIMSZ, HIDSZ, (const float*)nullptr,
      (uint16_t*)nullptr, 0, 0);
}